// Round 5
// baseline (166.554 us; speedup 1.0000x reference)
//
#include <hip/hip_runtime.h>
#include <hip/hip_fp16.h>
#include <math.h>

constexpr int NFFT = 256;
constexpr int HOP  = 216;
constexpr int PAD  = 20;

// LDS float-index layout (one region, phases alias across barriers):
//  plane   [0..4352)  : 16 fm x (16 rows x stride 17)  -- fwd/inv transposes
//  P1      [0..2103)  : md1 |X|^2 partials, per-frame stride 264 (aliases plane)
//  IPAD    [2112..4800): skewed padded intensity, per-frame stride 336
//  C(f16x2)[0..2048)  : packed (cr,ci) per bin (aliases plane/P1, both dead)
constexpr int FMP  = 272;
constexpr int PRS  = 264;
constexpr int IPB  = 2112;
constexpr int IPS2 = 336;
constexpr int SMF  = 4800;   // 19.2 KB

__device__ __forceinline__ void cmul(float& dr, float& di, float ar, float ai, float br, float bi) {
    dr = ar * br - ai * bi;
    di = ar * bi + ai * br;
}

constexpr float TC16[10] = {1.f, 0.92387953f, 0.70710678f, 0.38268343f, 0.f,
                            -0.38268343f, -0.70710678f, -0.92387953f, -1.f, -0.92387953f};
constexpr float TS16[10] = {0.f, 0.38268343f, 0.70710678f, 0.92387953f, 1.f,
                            0.92387953f, 0.70710678f, 0.38268343f, 0.f, -0.38268343f};

// In-register 16-point DFT, natural order in/out (verified rounds 3/4).
template<int SGN>
__device__ __forceinline__ void fft16(float xr[16], float xi[16]) {
    constexpr float S = (float)SGN;
    float tr[4][4], ti[4][4];
    #pragma unroll
    for (int n1 = 0; n1 < 4; ++n1) {
        float ar = xr[n1],      ai = xi[n1];
        float br = xr[n1 + 4],  bi = xi[n1 + 4];
        float cr = xr[n1 + 8],  ci = xi[n1 + 8];
        float dr = xr[n1 + 12], di = xi[n1 + 12];
        float Ar = ar + cr, Ai = ai + ci, Br = ar - cr, Bi = ai - ci;
        float Cr = br + dr, Ci = bi + di, Dr = br - dr, Di = bi - di;
        tr[n1][0] = Ar + Cr;      ti[n1][0] = Ai + Ci;
        tr[n1][2] = Ar - Cr;      ti[n1][2] = Ai - Ci;
        tr[n1][1] = Br - S * Di;  ti[n1][1] = Bi + S * Dr;
        tr[n1][3] = Br + S * Di;  ti[n1][3] = Bi - S * Dr;
    }
    #pragma unroll
    for (int n1 = 1; n1 < 4; ++n1) {
        #pragma unroll
        for (int k2 = 1; k2 < 4; ++k2) {
            const int m = n1 * k2;
            const float wr = TC16[m], wi = S * TS16[m];
            float vr, vi;
            cmul(vr, vi, tr[n1][k2], ti[n1][k2], wr, wi);
            tr[n1][k2] = vr; ti[n1][k2] = vi;
        }
    }
    #pragma unroll
    for (int k2 = 0; k2 < 4; ++k2) {
        float ar = tr[0][k2], ai = ti[0][k2];
        float br = tr[1][k2], bi = ti[1][k2];
        float cr = tr[2][k2], ci = ti[2][k2];
        float dr = tr[3][k2], di = ti[3][k2];
        float Ar = ar + cr, Ai = ai + ci, Br = ar - cr, Bi = ai - ci;
        float Cr = br + dr, Ci = bi + di, Dr = br - dr, Di = bi - di;
        xr[k2]      = Ar + Cr;     xi[k2]      = Ai + Ci;
        xr[k2 + 8]  = Ar - Cr;     xi[k2 + 8]  = Ai - Ci;
        xr[k2 + 4]  = Br - S * Di; xi[k2 + 4]  = Bi + S * Dr;
        xr[k2 + 12] = Br + S * Di; xi[k2 + 12] = Bi - S * Dr;
    }
}

// Sequential twiddle application: x[k] *= W^(k), W = (wr0, wi0). Only 2 live regs.
__device__ __forceinline__ void twiddle_seq(float xr[16], float xi[16], float wr0, float wi0) {
    float wkr = wr0, wki = wi0;
    #pragma unroll
    for (int k = 1; k < 16; ++k) {
        float vr, vi;
        cmul(vr, vi, xr[k], xi[k], wkr, wki);
        xr[k] = vr; xi[k] = vi;
        if (k < 15) {
            float nr, ni;
            cmul(nr, ni, wkr, wki, wr0, wi0);
            wkr = nr; wki = ni;
        }
    }
}

// Zero only the double-covered overlap stripes (atomicAdd targets).
__global__ __launch_bounds__(256)
void zero_overlap(float4* __restrict__ out4, int B, int steps, int Lout) {
    const int total = B * (steps - 1) * 40;
    for (int idx = blockIdx.x * 256 + threadIdx.x; idx < total; idx += gridDim.x * 256) {
        const int j  = idx / 40;
        const int r4 = idx - j * 40;
        const int b  = j / (steps - 1);
        const int s  = j - b * (steps - 1) + 1;
        out4[(size_t)b * Lout + (size_t)s * HOP - PAD + r4] = make_float4(0.f, 0.f, 0.f, 0.f);
    }
}

// Block = 256 threads = 8 frames x 2 modes x 16 lanes.
__global__ __launch_bounds__(256, 8)
void eq_pbc_kernel(const float* __restrict__ x_real,
                   const float* __restrict__ x_imag,
                   const float* __restrict__ task_info,
                   const float* __restrict__ h_real,
                   const float* __restrict__ h_imag,
                   float* __restrict__ out,
                   int B, int L, int steps)
{
    __shared__ __align__(16) float SM[SMF];

    const int tid = threadIdx.x;
    const int i   = tid & 15;
    const int fm  = tid >> 4;     // 0..15
    const int fr  = tid >> 5;     // 0..7
    const int md  = fm & 1;

    const int G = B * steps;
    int g = blockIdx.x * 8 + fr;
    const bool valid = (g < G);
    if (!valid) g = G - 1;
    const int b  = g / steps;
    const int s  = g - b * steps;
    const int l0 = s * HOP;

    float sb, cb;
    __sincosf(-6.2831853071795864f * (1.0f / 256.0f) * (float)i, &sb, &cb);

    // ---- load: thread holds x[l0 + i + 16*n2] for its mode ----
    float xr[16], xi[16];
    {
        const size_t base = ((size_t)b * L + l0) * 2 + (size_t)(2 * i + md);
        #pragma unroll
        for (int n2 = 0; n2 < 16; ++n2) {
            xr[n2] = x_real[base + 32 * n2];
            xi[n2] = x_imag[base + 32 * n2];
        }
    }

    // ---- forward step A + twiddle W256^{i*k2} ----
    fft16<-1>(xr, xi);
    twiddle_seq(xr, xi, cb, sb);

    // ---- forward transpose, single-component plane ----
    const int tb = fm * FMP;
    #pragma unroll
    for (int k = 0; k < 16; ++k) SM[tb + i * 17 + k] = xr[k];
    __syncthreads();                          // B1
    #pragma unroll
    for (int n1 = 0; n1 < 16; ++n1) xr[n1] = SM[tb + n1 * 17 + i];
    __syncthreads();                          // B2
    #pragma unroll
    for (int k = 0; k < 16; ++k) SM[tb + i * 17 + k] = xi[k];
    __syncthreads();                          // B3
    #pragma unroll
    for (int n1 = 0; n1 < 16; ++n1) xi[n1] = SM[tb + n1 * 17 + i];

    // ---- forward step B: X[f = i + 16*k1] in reg k1 ----
    fft16<-1>(xr, xi);
    __syncthreads();                          // B4 (plane reads done)

    // ---- intensity: md1 stores partials; md0 combines + skewed pad scatter ----
    if (md) {
        #pragma unroll
        for (int k1 = 0; k1 < 16; ++k1)
            SM[fr * PRS + i + 16 * k1] = xr[k1] * xr[k1] + xi[k1] * xi[k1];
    }
    __syncthreads();                          // B5
    if (!md) {
        #pragma unroll
        for (int k1 = 0; k1 < 16; ++k1) {
            const int f = i + 16 * k1;
            const float v = xr[k1] * xr[k1] + xi[k1] * xi[k1] + SM[fr * PRS + f];
            const int p = f + PAD;
            SM[IPB + fr * IPS2 + p + (p >> 3)] = v;
            if (f < PAD)  { const int p2 = f + 276; SM[IPB + fr * IPS2 + p2 + (p2 >> 3)] = v; }
            if (f >= 236) { const int p3 = f - 236; SM[IPB + fr * IPS2 + p3 + (p3 >> 3)] = v; }
        }
    }
    __syncthreads();                          // B6 (IPAD ready)

    // ---- FIR: thread u of frame frq -> outputs 8u..8u+7, streaming 8-deep window ----
    {
        const int u   = tid & 31;
        const int frq = tid >> 5;
        int g2 = blockIdx.x * 8 + frq;
        if (g2 >= G) g2 = G - 1;
        const int b2 = g2 / steps;
        const float* ipb = &SM[IPB + frq * IPS2 + 9 * u];
        float win[8];
        #pragma unroll
        for (int j = 0; j < 8; ++j) win[j] = ipb[j + (j >> 3)];
        float phr[8], phq[8];
        #pragma unroll
        for (int o = 0; o < 8; ++o) { phr[o] = 0.f; phq[o] = 0.f; }
        #pragma unroll
        for (int t = 0; t < 41; ++t) {
            const float htr = h_real[t], hti = h_imag[t];
            #pragma unroll
            for (int o = 0; o < 8; ++o) {
                const float wv = win[(t + o) & 7];
                phr[o] = fmaf(wv, htr, phr[o]);
                phq[o] = fmaf(wv, hti, phq[o]);
            }
            if (t < 40) { const int j = t + 8; win[t & 7] = ipb[j + (j >> 3)]; }
        }
        const float P = exp2f(task_info[4 * b2] * 0.33219280948873623f) * 0.5f;
        unsigned* C = (unsigned*)SM;          // f16x2-packed c, [0..2048)
        #pragma unroll
        for (int o = 0; o < 8; ++o) {
            __half2 h2 = __floats2half2_rn(1.0f - P * phq[o], P * phr[o]);
            C[frq * 256 + 8 * u + o] = *(unsigned*)&h2;
        }
    }
    __syncthreads();                          // B7 (C ready)

    // ---- modulate X[f] *= c[f] ----
    {
        const unsigned* C = (const unsigned*)SM;
        #pragma unroll
        for (int k1 = 0; k1 < 16; ++k1) {
            const unsigned cu = C[fr * 256 + i + 16 * k1];
            const __half2 h2 = *(const __half2*)&cu;
            const float cr_ = __low2float(h2);
            const float ci_ = __high2float(h2);
            const float vr = xr[k1] * cr_ - xi[k1] * ci_;
            const float vi = xr[k1] * ci_ + xi[k1] * cr_;
            xr[k1] = vr; xi[k1] = vi;
        }
    }

    // ---- inverse step A + conj twiddle ----
    fft16<1>(xr, xi);
    twiddle_seq(xr, xi, cb, -sb);
    __syncthreads();                          // B8 (C reads done; plane reusable)

    // ---- inverse transpose ----
    #pragma unroll
    for (int k = 0; k < 16; ++k) SM[tb + i * 17 + k] = xr[k];
    __syncthreads();                          // B9
    #pragma unroll
    for (int k2 = 0; k2 < 16; ++k2) xr[k2] = SM[tb + k2 * 17 + i];
    __syncthreads();                          // B10
    #pragma unroll
    for (int k = 0; k < 16; ++k) SM[tb + i * 17 + k] = xi[k];
    __syncthreads();                          // B11
    #pragma unroll
    for (int k2 = 0; k2 < 16; ++k2) xi[k2] = SM[tb + k2 * 17 + i];

    // ---- inverse step B: y[i + 16*n2] (x256) ----
    fft16<1>(xr, xi);

    // ---- OLA + wsum + crop ----
    if (valid) {
        const int Lout = L - 2 * PAD;
        float* obase = out + (size_t)b * Lout * 4 + md * 2;
        #pragma unroll
        for (int n2 = 0; n2 < 16; ++n2) {
            const int n  = i + 16 * n2;
            const int la = l0 + n;
            if (la < PAD || la >= L - PAD) continue;
            const bool ov = (n < NFFT - HOP && s > 0) || (n >= HOP && s + 1 < steps);
            const float sc = (ov ? 0.5f : 1.0f) * (1.0f / 256.0f);
            float* p = obase + (size_t)(la - PAD) * 4;
            const float vr = xr[n2] * sc, vi = xi[n2] * sc;
            if (ov) { atomicAdd(p, vr); atomicAdd(p + 1, vi); }
            else    { *(float2*)p = make_float2(vr, vi); }
        }
    }
}

extern "C" void kernel_launch(void* const* d_in, const int* in_sizes, int n_in,
                              void* d_out, int out_size, void* d_ws, size_t ws_size,
                              hipStream_t stream) {
    const float* x_real    = (const float*)d_in[0];
    const float* x_imag    = (const float*)d_in[1];
    const float* task_info = (const float*)d_in[2];
    const float* h_real    = (const float*)d_in[3];
    const float* h_imag    = (const float*)d_in[4];

    const int B     = in_sizes[2] / 4;
    const int L     = in_sizes[0] / (B * 2);
    const int steps = (L - NFFT) / HOP + 1;
    const int G     = B * steps;
    const int Lout  = L - 2 * PAD;

    if (steps > 1) {
        const int total4 = B * (steps - 1) * 40;
        const int zb = (total4 + 255) / 256;
        zero_overlap<<<zb, 256, 0, stream>>>((float4*)d_out, B, steps, Lout);
    }

    eq_pbc_kernel<<<(G + 7) / 8, 256, 0, stream>>>(
        x_real, x_imag, task_info, h_real, h_imag, (float*)d_out, B, L, steps);
}

// Round 6
// 116.771 us; speedup vs baseline: 1.4263x; 1.4263x over previous
//
#include <hip/hip_runtime.h>
#include <hip/hip_fp16.h>
#include <math.h>

constexpr int NFFT = 256;
constexpr int HOP  = 216;
constexpr int PAD  = 20;

// LDS layout (float indices), phases alias time-disjointly:
//  plane [0..1088)      : 4 fm x (16 rows x stride 17)  -- fwd/inv transposes
//  C     [0..520) uints : f16x2-packed c, stride 264/frame (aliases plane)
//  IPAD  [544..1216)    : skewed padded intensity, stride 336/frame
constexpr int CBS = 264;              // C stride per frame (uints)
constexpr int IPB = 544;              // IPAD base (float idx)
constexpr int IPS = 336;              // IPAD stride per frame
constexpr int SMF = IPB + 2 * IPS;    // 1216 floats = 4864 B

__device__ __forceinline__ void cmul(float& dr, float& di, float ar, float ai, float br, float bi) {
    dr = ar * br - ai * bi;
    di = ar * bi + ai * br;
}

constexpr float TC16[10] = {1.f, 0.92387953f, 0.70710678f, 0.38268343f, 0.f,
                            -0.38268343f, -0.70710678f, -0.92387953f, -1.f, -0.92387953f};
constexpr float TS16[10] = {0.f, 0.38268343f, 0.70710678f, 0.92387953f, 1.f,
                            0.92387953f, 0.70710678f, 0.38268343f, 0.f, -0.38268343f};

// In-register 16-point DFT, natural order in/out (verified rounds 3-5).
template<int SGN>
__device__ __forceinline__ void fft16(float xr[16], float xi[16]) {
    constexpr float S = (float)SGN;
    float tr[4][4], ti[4][4];
    #pragma unroll
    for (int n1 = 0; n1 < 4; ++n1) {
        float ar = xr[n1],      ai = xi[n1];
        float br = xr[n1 + 4],  bi = xi[n1 + 4];
        float cr = xr[n1 + 8],  ci = xi[n1 + 8];
        float dr = xr[n1 + 12], di = xi[n1 + 12];
        float Ar = ar + cr, Ai = ai + ci, Br = ar - cr, Bi = ai - ci;
        float Cr = br + dr, Ci = bi + di, Dr = br - dr, Di = bi - di;
        tr[n1][0] = Ar + Cr;      ti[n1][0] = Ai + Ci;
        tr[n1][2] = Ar - Cr;      ti[n1][2] = Ai - Ci;
        tr[n1][1] = Br - S * Di;  ti[n1][1] = Bi + S * Dr;
        tr[n1][3] = Br + S * Di;  ti[n1][3] = Bi - S * Dr;
    }
    #pragma unroll
    for (int n1 = 1; n1 < 4; ++n1) {
        #pragma unroll
        for (int k2 = 1; k2 < 4; ++k2) {
            const int m = n1 * k2;
            const float wr = TC16[m], wi = S * TS16[m];
            float vr, vi;
            cmul(vr, vi, tr[n1][k2], ti[n1][k2], wr, wi);
            tr[n1][k2] = vr; ti[n1][k2] = vi;
        }
    }
    #pragma unroll
    for (int k2 = 0; k2 < 4; ++k2) {
        float ar = tr[0][k2], ai = ti[0][k2];
        float br = tr[1][k2], bi = ti[1][k2];
        float cr = tr[2][k2], ci = ti[2][k2];
        float dr = tr[3][k2], di = ti[3][k2];
        float Ar = ar + cr, Ai = ai + ci, Br = ar - cr, Bi = ai - ci;
        float Cr = br + dr, Ci = bi + di, Dr = br - dr, Di = bi - di;
        xr[k2]      = Ar + Cr;     xi[k2]      = Ai + Ci;
        xr[k2 + 8]  = Ar - Cr;     xi[k2 + 8]  = Ai - Ci;
        xr[k2 + 4]  = Br - S * Di; xi[k2 + 4]  = Bi + S * Dr;
        xr[k2 + 12] = Br + S * Di; xi[k2 + 12] = Bi - S * Dr;
    }
}

// x[k] *= W^k sequentially (2 live regs).
__device__ __forceinline__ void twiddle_seq(float xr[16], float xi[16], float wr0, float wi0) {
    float wkr = wr0, wki = wi0;
    #pragma unroll
    for (int k = 1; k < 16; ++k) {
        float vr, vi;
        cmul(vr, vi, xr[k], xi[k], wkr, wki);
        xr[k] = vr; xi[k] = vi;
        if (k < 15) {
            float nr, ni;
            cmul(nr, ni, wkr, wki, wr0, wi0);
            wkr = nr; wki = ni;
        }
    }
}

// Zero only the double-covered overlap stripes (atomicAdd targets).
__global__ __launch_bounds__(256)
void zero_overlap(float4* __restrict__ out4, int B, int steps, int Lout) {
    const int total = B * (steps - 1) * 40;
    for (int idx = blockIdx.x * 256 + threadIdx.x; idx < total; idx += gridDim.x * 256) {
        const int j  = idx / 40;
        const int r4 = idx - j * 40;
        const int b  = j / (steps - 1);
        const int s  = j - b * (steps - 1) + 1;
        out4[(size_t)b * Lout + (size_t)s * HOP - PAD + r4] = make_float4(0.f, 0.f, 0.f, 0.f);
    }
}

// ONE WAVE per block: 64 threads = 2 frames x 2 modes x 16 lanes.
// All __syncthreads() are single-wave (near-free); waves are fully independent.
__global__ __launch_bounds__(64)
void eq_pbc_kernel(const float* __restrict__ x_real,
                   const float* __restrict__ x_imag,
                   const float* __restrict__ task_info,
                   const float* __restrict__ h_real,
                   const float* __restrict__ h_imag,
                   float* __restrict__ out,
                   int B, int L, int steps)
{
    __shared__ __align__(16) float SM[SMF];

    const int tid = threadIdx.x;
    const int i   = tid & 15;
    const int fm  = tid >> 4;     // 0..3
    const int fr  = fm >> 1;      // frame-local 0..1
    const int md  = fm & 1;

    const int G = B * steps;
    int g = blockIdx.x * 2 + fr;
    const bool valid = (g < G);
    if (!valid) g = G - 1;
    const int b  = g / steps;
    const int s  = g - b * steps;
    const int l0 = s * HOP;

    float sb, cb;
    __sincosf(-6.2831853071795864f * (1.0f / 256.0f) * (float)i, &sb, &cb);

    // ---- load: thread holds x[l0 + i + 16*n2] for its (frame, mode) ----
    float xr[16], xi[16];
    {
        const size_t base = ((size_t)b * L + l0) * 2 + (size_t)(2 * i + md);
        #pragma unroll
        for (int n2 = 0; n2 < 16; ++n2) {
            xr[n2] = x_real[base + 32 * n2];
            xi[n2] = x_imag[base + 32 * n2];
        }
    }

    // ---- forward step A + twiddle W256^{i*k2} ----
    fft16<-1>(xr, xi);
    twiddle_seq(xr, xi, cb, sb);

    // ---- forward transpose (single-component plane, stride 17) ----
    const int tb = fm * 272;
    #pragma unroll
    for (int k = 0; k < 16; ++k) SM[tb + i * 17 + k] = xr[k];
    __syncthreads();
    #pragma unroll
    for (int n1 = 0; n1 < 16; ++n1) xr[n1] = SM[tb + n1 * 17 + i];
    __syncthreads();
    #pragma unroll
    for (int k = 0; k < 16; ++k) SM[tb + i * 17 + k] = xi[k];
    __syncthreads();
    #pragma unroll
    for (int n1 = 0; n1 < 16; ++n1) xi[n1] = SM[tb + n1 * 17 + i];

    // ---- forward step B: X[f = i + 16*k1] in reg k1 ----
    fft16<-1>(xr, xi);
    __syncthreads();   // plane reads complete before IPAD (aliased) writes

    // ---- intensity: combine modes via one shuffle, scatter to skewed IPAD ----
    {
        float* ipf = &SM[IPB + fr * IPS];
        #pragma unroll
        for (int k1 = 0; k1 < 16; ++k1) {
            float v = xr[k1] * xr[k1] + xi[k1] * xi[k1];
            v += __shfl_xor(v, 16);        // lane(fm0,i) <-> lane(fm1,i): mode sum
            // md0 lanes write k1 0..7 (+right pad), md1 lanes write k1 8..15 (+left pad)
            if (!md && k1 < 8) {
                const int f = i + 16 * k1, p = f + PAD;
                ipf[p + (p >> 3)] = v;
                if (f < PAD) { const int p2 = f + 276; ipf[p2 + (p2 >> 3)] = v; }
            }
            if (md && k1 >= 8) {
                const int f = i + 16 * k1, p = f + PAD;
                ipf[p + (p >> 3)] = v;
                if (f >= 236) { const int p3 = f - 236; ipf[p3 + (p3 >> 3)] = v; }
            }
        }
    }
    __syncthreads();

    // ---- FIR: thread u of frame frq -> outputs 8u..8u+7, streaming ring window ----
    {
        const int u   = tid & 31;
        const int frq = tid >> 5;
        int g2 = blockIdx.x * 2 + frq;
        if (g2 >= G) g2 = G - 1;
        const int b2 = g2 / steps;
        const float* ipb = &SM[IPB + frq * IPS + 9 * u];   // 9u = 8u + (8u>>3) skew
        float win[8];
        #pragma unroll
        for (int j = 0; j < 8; ++j) win[j] = ipb[j + (j >> 3)];
        float phr[8], phq[8];
        #pragma unroll
        for (int o = 0; o < 8; ++o) { phr[o] = 0.f; phq[o] = 0.f; }
        #pragma unroll
        for (int t = 0; t < 41; ++t) {
            const float htr = h_real[t], hti = h_imag[t];
            #pragma unroll
            for (int o = 0; o < 8; ++o) {
                const float wv = win[(t + o) & 7];
                phr[o] = fmaf(wv, htr, phr[o]);
                phq[o] = fmaf(wv, hti, phq[o]);
            }
            if (t < 40) { const int j = t + 8; win[t & 7] = ipb[j + (j >> 3)]; }
        }
        const float P = exp2f(task_info[4 * b2] * 0.33219280948873623f) * 0.5f;
        unsigned* C = (unsigned*)SM;
        #pragma unroll
        for (int o = 0; o < 8; ++o) {
            __half2 h2 = __floats2half2_rn(1.0f - P * phq[o], P * phr[o]);
            C[frq * CBS + 8 * u + o] = *(unsigned*)&h2;
        }
    }
    __syncthreads();

    // ---- modulate X[f] *= c[f] ----
    {
        const unsigned* C = (const unsigned*)SM;
        #pragma unroll
        for (int k1 = 0; k1 < 16; ++k1) {
            const unsigned cu = C[fr * CBS + i + 16 * k1];
            const __half2 h2 = *(const __half2*)&cu;
            const float cr_ = __low2float(h2);
            const float ci_ = __high2float(h2);
            const float vr = xr[k1] * cr_ - xi[k1] * ci_;
            const float vi = xr[k1] * ci_ + xi[k1] * cr_;
            xr[k1] = vr; xi[k1] = vi;
        }
    }

    // ---- inverse step A + conj twiddle ----
    fft16<1>(xr, xi);
    twiddle_seq(xr, xi, cb, -sb);
    __syncthreads();   // C reads done; plane region reusable

    // ---- inverse transpose ----
    #pragma unroll
    for (int k = 0; k < 16; ++k) SM[tb + i * 17 + k] = xr[k];
    __syncthreads();
    #pragma unroll
    for (int k2 = 0; k2 < 16; ++k2) xr[k2] = SM[tb + k2 * 17 + i];
    __syncthreads();
    #pragma unroll
    for (int k = 0; k < 16; ++k) SM[tb + i * 17 + k] = xi[k];
    __syncthreads();
    #pragma unroll
    for (int k2 = 0; k2 < 16; ++k2) xi[k2] = SM[tb + k2 * 17 + i];

    // ---- inverse step B: y[i + 16*n2] (x256) ----
    fft16<1>(xr, xi);

    // ---- OLA + wsum + crop ----
    if (valid) {
        const int Lout = L - 2 * PAD;
        float* obase = out + (size_t)b * Lout * 4 + md * 2;
        #pragma unroll
        for (int n2 = 0; n2 < 16; ++n2) {
            const int n  = i + 16 * n2;
            const int la = l0 + n;
            if (la < PAD || la >= L - PAD) continue;
            const bool ov = (n < NFFT - HOP && s > 0) || (n >= HOP && s + 1 < steps);
            const float sc = (ov ? 0.5f : 1.0f) * (1.0f / 256.0f);
            float* p = obase + (size_t)(la - PAD) * 4;
            const float vr = xr[n2] * sc, vi = xi[n2] * sc;
            if (ov) { atomicAdd(p, vr); atomicAdd(p + 1, vi); }
            else    { *(float2*)p = make_float2(vr, vi); }
        }
    }
}

extern "C" void kernel_launch(void* const* d_in, const int* in_sizes, int n_in,
                              void* d_out, int out_size, void* d_ws, size_t ws_size,
                              hipStream_t stream) {
    const float* x_real    = (const float*)d_in[0];
    const float* x_imag    = (const float*)d_in[1];
    const float* task_info = (const float*)d_in[2];
    const float* h_real    = (const float*)d_in[3];
    const float* h_imag    = (const float*)d_in[4];

    const int B     = in_sizes[2] / 4;
    const int L     = in_sizes[0] / (B * 2);
    const int steps = (L - NFFT) / HOP + 1;
    const int G     = B * steps;
    const int Lout  = L - 2 * PAD;

    if (steps > 1) {
        const int total4 = B * (steps - 1) * 40;
        const int zb = (total4 + 255) / 256;
        zero_overlap<<<zb, 256, 0, stream>>>((float4*)d_out, B, steps, Lout);
    }

    eq_pbc_kernel<<<(G + 1) / 2, 64, 0, stream>>>(
        x_real, x_imag, task_info, h_real, h_imag, (float*)d_out, B, L, steps);
}